// Round 4
// baseline (98.260 us; speedup 1.0000x reference)
//
#include <hip/hip_runtime.h>
#include <math.h>

#define TT 512
#define DD 256
#define BIGF 9999.0f
#define KK 8
#define NBLK 128   // 4 rows per block

// ws layout (bytes)
#define HT_OFF    0          // float ht[DD][TT]   512 KB  transposed H
#define A_OFF     524288     // float a[TT]
#define B_OFF     526336     // float b[TT]
#define MB_OFF    528384     // ull   mb[TT][4]
#define LOSS_OFF  544768     // float loss[NBLK]
#define CNT_OFF   546816     // int cnt1, cnt2  (zeroed by memset node each call)

__device__ __forceinline__ void grid_barrier(int* cnt, int n) {
  __syncthreads();  // compiler drains vmcnt before s_barrier
  if (threadIdx.x == 0) {
    __threadfence();  // release: L2 writeback (covers whole block's stores)
    __hip_atomic_fetch_add(cnt, 1, __ATOMIC_ACQ_REL, __HIP_MEMORY_SCOPE_AGENT);
    while (__hip_atomic_load(cnt, __ATOMIC_RELAXED, __HIP_MEMORY_SCOPE_AGENT) < n)
      __builtin_amdgcn_s_sleep(2);
    __threadfence();  // acquire: invalidate stale cached lines
  }
  __syncthreads();
}

__global__ __launch_bounds__(256) void fused_kernel(
    const float* __restrict__ X, const float* __restrict__ H,
    const float* __restrict__ C, const int* __restrict__ M,
    float* __restrict__ ht, float* __restrict__ A, float* __restrict__ B,
    unsigned long long* __restrict__ MB, float* __restrict__ LOSS,
    int* __restrict__ CNT, float* __restrict__ out) {
  const int b = blockIdx.x;
  const int t = threadIdx.x;
  const int wid = t >> 6, lane = t & 63;
  const int i0 = 4 * b;

  __shared__ float sA[4][4], sB[4][4], sM[4][4];
  __shared__ float s_msep;
  __shared__ float dl[4][TT];
  __shared__ float nrm[4][TT];

  // ---------------- Phase 1: per-row stats + transpose ----------------
  float hv[4];
#pragma unroll
  for (int r = 0; r < 4; ++r) {
    const int idx = (i0 + r) * DD + t;
    const float x = X[idx], h = H[idx], c = C[idx];
    const int m = M[idx];
    hv[r] = h;
    const float e = m ? (x - h + c) : 0.0f;
    float pm = e * e, ph = h, ph2 = h * h;
#pragma unroll
    for (int s = 1; s < 64; s <<= 1) {
      pm  += __shfl_xor(pm, s);
      ph  += __shfl_xor(ph, s);
      ph2 += __shfl_xor(ph2, s);
    }
    const unsigned long long bal = __ballot(m != 0);
    if (lane == 0) {
      sA[r][wid] = ph; sB[r][wid] = ph2; sM[r][wid] = pm;
      MB[(i0 + r) * 4 + wid] = bal;
    }
  }
  // transpose write: ht[d][i0..i0+3], 16B aligned
  float4 hw = make_float4(hv[0], hv[1], hv[2], hv[3]);
  *(float4*)(ht + t * TT + i0) = hw;
  __syncthreads();
  if (t < 4) {
    A[i0 + t] = sA[t][0] + sA[t][1] + sA[t][2] + sA[t][3];
    B[i0 + t] = sB[t][0] + sB[t][1] + sB[t][2] + sB[t][3];
  }
  if (t == 0) {
    float ms = 0.0f;
#pragma unroll
    for (int r = 0; r < 4; ++r)
#pragma unroll
      for (int wq = 0; wq < 4; ++wq) ms += sM[r][wq];
    s_msep = ms;
  }

  grid_barrier(&CNT[0], NBLK);

  // ---------------- Phase 2: scores (r2-proven structure) ----------------
  float acc[4][2] = {{0.f, 0.f}, {0.f, 0.f}, {0.f, 0.f}, {0.f, 0.f}};
  {
    const float* __restrict__ pi = ht + i0;
    const float* __restrict__ pj = ht + 2 * t;
#pragma unroll 8
    for (int d = 0; d < DD; ++d) {
      const float4 hi = *(const float4*)(pi + d * TT);   // uniform
      const float2 hj = *(const float2*)(pj + d * TT);   // coalesced
      acc[0][0] += hi.x * hj.x; acc[0][1] += hi.x * hj.y;
      acc[1][0] += hi.y * hj.x; acc[1][1] += hi.y * hj.y;
      acc[2][0] += hi.z * hj.x; acc[2][1] += hi.z * hj.y;
      acc[3][0] += hi.w * hj.x; acc[3][1] += hi.w * hj.y;
    }
  }

  float ai[4], bi[4];
  unsigned long long mi[4][4];
#pragma unroll
  for (int r = 0; r < 4; ++r) {
    ai[r] = A[i0 + r];
    bi[r] = B[i0 + r];
#pragma unroll
    for (int c = 0; c < 4; ++c) mi[r][c] = MB[(i0 + r) * 4 + c];
  }

#pragma unroll
  for (int jj = 0; jj < 2; ++jj) {
    const int j = 2 * t + jj;
    const float aj = A[j], bj = B[j];
    const unsigned long long m0 = MB[j * 4 + 0], m1 = MB[j * 4 + 1],
                             m2 = MB[j * 4 + 2], m3 = MB[j * 4 + 3];
#pragma unroll
    for (int r = 0; r < 4; ++r) {
      const float dot = acc[r][jj];
      const float s2 = bi[r] + bj - 2.0f * dot;
      const float s1 = ai[r] - aj;
      const float var = (s2 - s1 * s1 * (1.0f / DD)) * (1.0f / (DD - 1));
      const bool diff = (m0 != mi[r][0]) | (m1 != mi[r][1]) |
                        (m2 != mi[r][2]) | (m3 != mi[r][3]);
      const bool valid = diff && (j != i0 + r);
      dl[r][j] = valid ? sqrtf(fmaxf(var, 0.0f)) : BIGF;
      nrm[r][j] = sqrtf(fmaxf(s2, 0.0f));
    }
  }
  __syncthreads();

  // wave w -> row i0+w: iterative top-8 smallest, lowest-index tie-break
  __shared__ float s_rl[4];
  {
    const int w = wid;
    float cv[8];
#pragma unroll
    for (int c = 0; c < 8; ++c) cv[c] = dl[w][lane + 64 * c];

    float kv[KK];
    int ki[KK];
#pragma unroll
    for (int k = 0; k < KK; ++k) {
      float bv = cv[0];
      int bc = 0;
#pragma unroll
      for (int c = 1; c < 8; ++c) {
        if (cv[c] < bv) { bv = cv[c]; bc = c; }
      }
      int bidx = lane + 64 * bc;
#pragma unroll
      for (int s = 1; s < 64; s <<= 1) {
        const float ov = __shfl_xor(bv, s);
        const int oi = __shfl_xor(bidx, s);
        if (ov < bv || (ov == bv && oi < bidx)) { bv = ov; bidx = oi; }
      }
      kv[k] = bv;
      ki[k] = bidx;
      const int csel = bidx >> 6;
      const bool mine = (bidx & 63) == lane;
#pragma unroll
      for (int c = 0; c < 8; ++c) {
        if (mine && c == csel) cv[c] = BIGF;
      }
    }
    float wsum = 0.0f, rl = 0.0f;
#pragma unroll
    for (int k = 0; k < KK; ++k) {
      const float e = expf(kv[0] - kv[k]);  // kv[0] = min score
      wsum += e;
      rl += e * nrm[w][ki[k]];
    }
    if (lane == 0) s_rl[w] = rl / wsum;
  }
  __syncthreads();
  if (t == 0)
    LOSS[b] = s_rl[0] + s_rl[1] + s_rl[2] + s_rl[3] + s_msep;

  // ---------------- Phase 3: block 0 deterministic final sum ----------------
  __syncthreads();  // drain LOSS store
  if (t == 0) {
    __threadfence();
    __hip_atomic_fetch_add(&CNT[1], 1, __ATOMIC_ACQ_REL, __HIP_MEMORY_SCOPE_AGENT);
  }
  if (b != 0) return;
  if (t == 0) {
    while (__hip_atomic_load(&CNT[1], __ATOMIC_RELAXED, __HIP_MEMORY_SCOPE_AGENT) < NBLK)
      __builtin_amdgcn_s_sleep(2);
    __threadfence();
  }
  __syncthreads();
  float v = (t < NBLK) ? LOSS[t] : 0.0f;
#pragma unroll
  for (int s = 1; s < 64; s <<= 1) v += __shfl_xor(v, s);
  __shared__ float sp[4];
  if (lane == 0) sp[wid] = v;
  __syncthreads();
  if (t == 0) out[0] = sp[0] + sp[1] + sp[2] + sp[3];
}

extern "C" void kernel_launch(void* const* d_in, const int* in_sizes, int n_in,
                              void* d_out, int out_size, void* d_ws, size_t ws_size,
                              hipStream_t stream) {
  const float* X = (const float*)d_in[0];
  const float* H = (const float*)d_in[1];
  const float* C = (const float*)d_in[2];
  const int* M = (const int*)d_in[3];
  float* out = (float*)d_out;

  char* ws = (char*)d_ws;
  float* ht = (float*)(ws + HT_OFF);
  float* A = (float*)(ws + A_OFF);
  float* B = (float*)(ws + B_OFF);
  unsigned long long* MB = (unsigned long long*)(ws + MB_OFF);
  float* LOSS = (float*)(ws + LOSS_OFF);
  int* CNT = (int*)(ws + CNT_OFF);

  // re-arm the barrier counters every call (also fixes poisoned/initial state)
  hipMemsetAsync(CNT, 0, 2 * sizeof(int), stream);
  fused_kernel<<<NBLK, 256, 0, stream>>>(X, H, C, M, ht, A, B, MB, LOSS, CNT, out);
}

// Round 5
// 37.790 us; speedup vs baseline: 2.6001x; 2.6001x over previous
//
#include <hip/hip_runtime.h>
#include <math.h>

#define TT 512
#define DD 256
#define BIGF 9999.0f
#define KK 8
#define NBLK 128   // 4 rows per block, both kernels

// ws layout (bytes)
#define HT_OFF    0          // float ht[DD][TT]   512 KB  transposed H
#define A_OFF     524288     // float a[TT]
#define B_OFF     526336     // float b[TT]
#define MB_OFF    528384     // ull   mb[TT][4]
#define MSEP_OFF  544768     // float msep4[NBLK]  per-4-row-group masked MSE
#define PART_OFF  545792     // float part[NBLK]   per-block partial losses
#define CNT_OFF   546816     // int   cnt

typedef unsigned long long ull;

__global__ __launch_bounds__(256) void prep_kernel(
    const float* __restrict__ X, const float* __restrict__ H,
    const float* __restrict__ C, const int* __restrict__ M,
    float* __restrict__ ht, float* __restrict__ A, float* __restrict__ B,
    ull* __restrict__ MB, float* __restrict__ MSEP4, int* __restrict__ CNT) {
  const int b = blockIdx.x;
  const int t = threadIdx.x;
  const int wid = t >> 6, lane = t & 63;
  const int i0 = 4 * b;
  if (b == 0 && t == 0) *CNT = 0;  // re-armed every call; kernel boundary publishes

  __shared__ float sA[4][4], sB[4][4], sM[4][4];
  float hv[4];
#pragma unroll
  for (int r = 0; r < 4; ++r) {
    const int idx = (i0 + r) * DD + t;
    const float x = X[idx], h = H[idx], c = C[idx];
    const int m = M[idx];
    hv[r] = h;
    const float e = m ? (x - h + c) : 0.0f;
    float pm = e * e, ph = h, ph2 = h * h;
#pragma unroll
    for (int s = 1; s < 64; s <<= 1) {
      pm  += __shfl_xor(pm, s);
      ph  += __shfl_xor(ph, s);
      ph2 += __shfl_xor(ph2, s);
    }
    const ull bal = __ballot(m != 0);
    if (lane == 0) {
      sA[r][wid] = ph; sB[r][wid] = ph2; sM[r][wid] = pm;
      MB[(i0 + r) * 4 + wid] = bal;
    }
  }
  // transpose write: ht[d=t][i0..i0+3], 16B aligned, full sectors
  *(float4*)(ht + t * TT + i0) = make_float4(hv[0], hv[1], hv[2], hv[3]);
  __syncthreads();
  if (t < 4) {
    A[i0 + t] = sA[t][0] + sA[t][1] + sA[t][2] + sA[t][3];
    B[i0 + t] = sB[t][0] + sB[t][1] + sB[t][2] + sB[t][3];
  }
  if (t == 0) {
    float ms = 0.0f;
#pragma unroll
    for (int r = 0; r < 4; ++r)
#pragma unroll
      for (int wq = 0; wq < 4; ++wq) ms += sM[r][wq];
    MSEP4[b] = ms;
  }
}

// 128 blocks x 256 threads; block owns rows i0..i0+3, thread t owns j={2t,2t+1}.
// Register outer product over transposed H; last-arriving block reduces.
__global__ __launch_bounds__(256) void score_kernel(
    const float* __restrict__ ht, const float* __restrict__ A,
    const float* __restrict__ B, const ull* __restrict__ MB,
    const float* __restrict__ MSEP4, float* __restrict__ PART,
    int* __restrict__ CNT, float* __restrict__ out) {
  __shared__ float dl[4][TT];
  __shared__ float nrm[4][TT];
  const int b = blockIdx.x;
  const int t = threadIdx.x;
  const int wid = t >> 6, lane = t & 63;
  const int i0 = 4 * b;

  float acc[4][2] = {{0.f, 0.f}, {0.f, 0.f}, {0.f, 0.f}, {0.f, 0.f}};
  {
    const float* __restrict__ pi = ht + i0;
    const float* __restrict__ pj = ht + 2 * t;
#pragma unroll 8
    for (int d = 0; d < DD; ++d) {
      const float4 hi = *(const float4*)(pi + d * TT);   // uniform, 1 line/wave
      const float2 hj = *(const float2*)(pj + d * TT);   // coalesced 512B/wave
      acc[0][0] += hi.x * hj.x; acc[0][1] += hi.x * hj.y;
      acc[1][0] += hi.y * hj.x; acc[1][1] += hi.y * hj.y;
      acc[2][0] += hi.z * hj.x; acc[2][1] += hi.z * hj.y;
      acc[3][0] += hi.w * hj.x; acc[3][1] += hi.w * hj.y;
    }
  }

  float ai[4], bi[4];
  ull mi[4][4];
#pragma unroll
  for (int r = 0; r < 4; ++r) {
    ai[r] = A[i0 + r];
    bi[r] = B[i0 + r];
#pragma unroll
    for (int c = 0; c < 4; ++c) mi[r][c] = MB[(i0 + r) * 4 + c];
  }

#pragma unroll
  for (int jj = 0; jj < 2; ++jj) {
    const int j = 2 * t + jj;
    const float aj = A[j], bj = B[j];
    const ull m0 = MB[j * 4 + 0], m1 = MB[j * 4 + 1],
              m2 = MB[j * 4 + 2], m3 = MB[j * 4 + 3];
#pragma unroll
    for (int r = 0; r < 4; ++r) {
      const float dot = acc[r][jj];
      const float s2 = bi[r] + bj - 2.0f * dot;
      const float s1 = ai[r] - aj;
      const float var = (s2 - s1 * s1 * (1.0f / DD)) * (1.0f / (DD - 1));
      const bool diff = (m0 != mi[r][0]) | (m1 != mi[r][1]) |
                        (m2 != mi[r][2]) | (m3 != mi[r][3]);
      const bool valid = diff && (j != i0 + r);
      dl[r][j] = valid ? sqrtf(fmaxf(var, 0.0f)) : BIGF;
      nrm[r][j] = sqrtf(fmaxf(s2, 0.0f));
    }
  }
  __syncthreads();

  // wave w -> row i0+w: iterative top-8 smallest, lowest-index tie-break
  __shared__ float s_rl[4];
  {
    const int w = wid;
    float cv[8];
#pragma unroll
    for (int c = 0; c < 8; ++c) cv[c] = dl[w][lane + 64 * c];

    float kv[KK];
    int ki[KK];
#pragma unroll
    for (int k = 0; k < KK; ++k) {
      float bv = cv[0];
      int bc = 0;
#pragma unroll
      for (int c = 1; c < 8; ++c) {
        if (cv[c] < bv) { bv = cv[c]; bc = c; }
      }
      int bidx = lane + 64 * bc;
#pragma unroll
      for (int s = 1; s < 64; s <<= 1) {
        const float ov = __shfl_xor(bv, s);
        const int oi = __shfl_xor(bidx, s);
        if (ov < bv || (ov == bv && oi < bidx)) { bv = ov; bidx = oi; }
      }
      kv[k] = bv;
      ki[k] = bidx;
      const int csel = bidx >> 6;
      const bool mine = (bidx & 63) == lane;
#pragma unroll
      for (int c = 0; c < 8; ++c) {
        if (mine && c == csel) cv[c] = BIGF;
      }
    }
    float wsum = 0.0f, rl = 0.0f;
#pragma unroll
    for (int k = 0; k < KK; ++k) {
      const float e = expf(kv[0] - kv[k]);  // kv[0] = min score
      wsum += e;
      rl += e * nrm[w][ki[k]];
    }
    if (lane == 0) s_rl[w] = rl / wsum;
  }
  __syncthreads();

  // ---- tail: publish partial, last-arriving block reduces (fixed order) ----
  __shared__ int s_done;
  if (t == 0) {
    PART[b] = s_rl[0] + s_rl[1] + s_rl[2] + s_rl[3] + MSEP4[b];
    __threadfence();  // release: PART[b] visible at coherence point
    const int old = __hip_atomic_fetch_add(CNT, 1, __ATOMIC_RELAXED,
                                           __HIP_MEMORY_SCOPE_AGENT);
    s_done = (old == NBLK - 1);
  }
  __syncthreads();
  if (s_done) {
    if (t == 0) __threadfence();  // acquire: invalidate stale cached PART lines
    __syncthreads();
    float v = (t < NBLK) ? PART[t] : 0.0f;
#pragma unroll
    for (int s = 1; s < 64; s <<= 1) v += __shfl_xor(v, s);
    __shared__ float sp[4];
    if (lane == 0) sp[wid] = v;
    __syncthreads();
    if (t == 0) out[0] = sp[0] + sp[1] + sp[2] + sp[3];
  }
}

extern "C" void kernel_launch(void* const* d_in, const int* in_sizes, int n_in,
                              void* d_out, int out_size, void* d_ws, size_t ws_size,
                              hipStream_t stream) {
  const float* X = (const float*)d_in[0];
  const float* H = (const float*)d_in[1];
  const float* C = (const float*)d_in[2];
  const int* M = (const int*)d_in[3];
  float* out = (float*)d_out;

  char* ws = (char*)d_ws;
  float* ht = (float*)(ws + HT_OFF);
  float* A = (float*)(ws + A_OFF);
  float* B = (float*)(ws + B_OFF);
  ull* MB = (ull*)(ws + MB_OFF);
  float* MSEP4 = (float*)(ws + MSEP_OFF);
  float* PART = (float*)(ws + PART_OFF);
  int* CNT = (int*)(ws + CNT_OFF);

  prep_kernel<<<NBLK, 256, 0, stream>>>(X, H, C, M, ht, A, B, MB, MSEP4, CNT);
  score_kernel<<<NBLK, 256, 0, stream>>>(ht, A, B, MB, MSEP4, PART, CNT, out);
}

// Round 6
// 34.898 us; speedup vs baseline: 2.8156x; 1.0829x over previous
//
#include <hip/hip_runtime.h>
#include <math.h>

#define TT 512
#define DD 256
#define BIGF 9999.0f
#define KK 8
#define NBLK 128   // 4 rows per block, both kernels

// ws layout (bytes)
#define HT_OFF    0          // float ht[DD][TT]   512 KB  transposed H
#define A_OFF     524288     // float a[TT]
#define B_OFF     526336     // float b[TT]
#define MB_OFF    528384     // ull   mb[TT][4]
#define MSEP_OFF  544768     // float msep4[NBLK]  per-4-row-group masked MSE

typedef unsigned long long ull;

__global__ __launch_bounds__(256) void prep_kernel(
    const float* __restrict__ X, const float* __restrict__ H,
    const float* __restrict__ C, const int* __restrict__ M,
    float* __restrict__ ht, float* __restrict__ A, float* __restrict__ B,
    ull* __restrict__ MB, float* __restrict__ MSEP4, float* __restrict__ out) {
  const int b = blockIdx.x;
  const int t = threadIdx.x;
  const int wid = t >> 6, lane = t & 63;
  const int i0 = 4 * b;
  if (b == 0 && t == 0) out[0] = 0.0f;  // re-arm accumulator every call

  __shared__ float sA[4][4], sB[4][4], sM[4][4];
  float hv[4];
#pragma unroll
  for (int r = 0; r < 4; ++r) {
    const int idx = (i0 + r) * DD + t;
    const float x = X[idx], h = H[idx], c = C[idx];
    const int m = M[idx];
    hv[r] = h;
    const float e = m ? (x - h + c) : 0.0f;
    float pm = e * e, ph = h, ph2 = h * h;
#pragma unroll
    for (int s = 1; s < 64; s <<= 1) {
      pm  += __shfl_xor(pm, s);
      ph  += __shfl_xor(ph, s);
      ph2 += __shfl_xor(ph2, s);
    }
    const ull bal = __ballot(m != 0);
    if (lane == 0) {
      sA[r][wid] = ph; sB[r][wid] = ph2; sM[r][wid] = pm;
      MB[(i0 + r) * 4 + wid] = bal;
    }
  }
  // transpose write: ht[d=t][i0..i0+3], 16B aligned, full sectors
  *(float4*)(ht + t * TT + i0) = make_float4(hv[0], hv[1], hv[2], hv[3]);
  __syncthreads();
  if (t < 4) {
    A[i0 + t] = sA[t][0] + sA[t][1] + sA[t][2] + sA[t][3];
    B[i0 + t] = sB[t][0] + sB[t][1] + sB[t][2] + sB[t][3];
  }
  if (t == 0) {
    float ms = 0.0f;
#pragma unroll
    for (int r = 0; r < 4; ++r)
#pragma unroll
      for (int wq = 0; wq < 4; ++wq) ms += sM[r][wq];
    MSEP4[b] = ms;
  }
}

// 128 blocks x 256 threads; block owns rows i0..i0+3, thread t owns j={2t,2t+1}.
// Register outer product over transposed H; tail = ONE atomicAdd per block
// (device-coherent without fences; FP-order noise << absmax threshold).
__global__ __launch_bounds__(256) void score_kernel(
    const float* __restrict__ ht, const float* __restrict__ A,
    const float* __restrict__ B, const ull* __restrict__ MB,
    const float* __restrict__ MSEP4, float* __restrict__ out) {
  __shared__ float dl[4][TT];
  __shared__ float nrm[4][TT];
  const int b = blockIdx.x;
  const int t = threadIdx.x;
  const int wid = t >> 6, lane = t & 63;
  const int i0 = 4 * b;

  float acc[4][2] = {{0.f, 0.f}, {0.f, 0.f}, {0.f, 0.f}, {0.f, 0.f}};
  {
    const float* __restrict__ pi = ht + i0;
    const float* __restrict__ pj = ht + 2 * t;
#pragma unroll 8
    for (int d = 0; d < DD; ++d) {
      const float4 hi = *(const float4*)(pi + d * TT);   // uniform, 1 line/wave
      const float2 hj = *(const float2*)(pj + d * TT);   // coalesced 512B/wave
      acc[0][0] += hi.x * hj.x; acc[0][1] += hi.x * hj.y;
      acc[1][0] += hi.y * hj.x; acc[1][1] += hi.y * hj.y;
      acc[2][0] += hi.z * hj.x; acc[2][1] += hi.z * hj.y;
      acc[3][0] += hi.w * hj.x; acc[3][1] += hi.w * hj.y;
    }
  }

  float ai[4], bi[4];
  ull mi[4][4];
#pragma unroll
  for (int r = 0; r < 4; ++r) {
    ai[r] = A[i0 + r];
    bi[r] = B[i0 + r];
#pragma unroll
    for (int c = 0; c < 4; ++c) mi[r][c] = MB[(i0 + r) * 4 + c];
  }

#pragma unroll
  for (int jj = 0; jj < 2; ++jj) {
    const int j = 2 * t + jj;
    const float aj = A[j], bj = B[j];
    const ull m0 = MB[j * 4 + 0], m1 = MB[j * 4 + 1],
              m2 = MB[j * 4 + 2], m3 = MB[j * 4 + 3];
#pragma unroll
    for (int r = 0; r < 4; ++r) {
      const float dot = acc[r][jj];
      const float s2 = bi[r] + bj - 2.0f * dot;
      const float s1 = ai[r] - aj;
      const float var = (s2 - s1 * s1 * (1.0f / DD)) * (1.0f / (DD - 1));
      const bool diff = (m0 != mi[r][0]) | (m1 != mi[r][1]) |
                        (m2 != mi[r][2]) | (m3 != mi[r][3]);
      const bool valid = diff && (j != i0 + r);
      dl[r][j] = valid ? sqrtf(fmaxf(var, 0.0f)) : BIGF;
      nrm[r][j] = sqrtf(fmaxf(s2, 0.0f));
    }
  }
  __syncthreads();

  // wave w -> row i0+w: iterative top-8 smallest, lowest-index tie-break
  __shared__ float s_rl[4];
  {
    const int w = wid;
    float cv[8];
#pragma unroll
    for (int c = 0; c < 8; ++c) cv[c] = dl[w][lane + 64 * c];

    float kv[KK];
    int ki[KK];
#pragma unroll
    for (int k = 0; k < KK; ++k) {
      float bv = cv[0];
      int bc = 0;
#pragma unroll
      for (int c = 1; c < 8; ++c) {
        if (cv[c] < bv) { bv = cv[c]; bc = c; }
      }
      int bidx = lane + 64 * bc;
#pragma unroll
      for (int s = 1; s < 64; s <<= 1) {
        const float ov = __shfl_xor(bv, s);
        const int oi = __shfl_xor(bidx, s);
        if (ov < bv || (ov == bv && oi < bidx)) { bv = ov; bidx = oi; }
      }
      kv[k] = bv;
      ki[k] = bidx;
      const int csel = bidx >> 6;
      const bool mine = (bidx & 63) == lane;
#pragma unroll
      for (int c = 0; c < 8; ++c) {
        if (mine && c == csel) cv[c] = BIGF;
      }
    }
    float wsum = 0.0f, rl = 0.0f;
#pragma unroll
    for (int k = 0; k < KK; ++k) {
      const float e = expf(kv[0] - kv[k]);  // kv[0] = min score
      wsum += e;
      rl += e * nrm[w][ki[k]];
    }
    if (lane == 0) s_rl[w] = rl / wsum;
  }
  __syncthreads();

  if (t == 0)
    atomicAdd(out, s_rl[0] + s_rl[1] + s_rl[2] + s_rl[3] + MSEP4[b]);
}

extern "C" void kernel_launch(void* const* d_in, const int* in_sizes, int n_in,
                              void* d_out, int out_size, void* d_ws, size_t ws_size,
                              hipStream_t stream) {
  const float* X = (const float*)d_in[0];
  const float* H = (const float*)d_in[1];
  const float* C = (const float*)d_in[2];
  const int* M = (const int*)d_in[3];
  float* out = (float*)d_out;

  char* ws = (char*)d_ws;
  float* ht = (float*)(ws + HT_OFF);
  float* A = (float*)(ws + A_OFF);
  float* B = (float*)(ws + B_OFF);
  ull* MB = (ull*)(ws + MB_OFF);
  float* MSEP4 = (float*)(ws + MSEP_OFF);

  prep_kernel<<<NBLK, 256, 0, stream>>>(X, H, C, M, ht, A, B, MB, MSEP4, out);
  score_kernel<<<NBLK, 256, 0, stream>>>(ht, A, B, MB, MSEP4, out);
}